// Round 23
// baseline (1782.195 us; speedup 1.0000x reference)
//
#include <hip/hip_runtime.h>

#define B_   256
#define T_   512
#define IN_  34
#define H_   80
#define L_   10
#define NC_  5
#define G4   320
#define NG   3          // wavefront depth: 3 layer-groups (passes 0..2 = layers 0..8)
#define TPB  (NG * G4)  // 960
#define HPS  96         // row: 2 slices x 48 f16 (40 used + 8 pad)

typedef _Float16 h2 __attribute__((ext_vector_type(2)));

template <int CTRL>
__device__ __forceinline__ float dpp_mov(float v) {
    return __int_as_float(__builtin_amdgcn_update_dpp(0, __float_as_int(v), CTRL, 0xF, 0xF, true));
}
__device__ __forceinline__ h2 bc(unsigned u) { return __builtin_bit_cast(h2, u); }

// Wavefront weights (layers 0..8): uint4 index (l*20 + n)*G4 + lane.
// Tail weights (layer 9, R14 layout): side 0 = W_ih[9] (producers), side 1 = W_hh[9] (chain).
__global__ void prep_kernel(const float* __restrict__ Wih0, const float* __restrict__ WihR,
                            const float* __restrict__ Whh,  const float* __restrict__ bih,
                            const float* __restrict__ bhh,
                            unsigned* __restrict__ w, float* __restrict__ bbuf,
                            unsigned* __restrict__ tw) {
    int idx = blockIdx.x * 256 + threadIdx.x;          // dword index
    const int ND = L_ * 20 * G4 * 4;                   // 256000 dwords
    if (idx < ND) {
        int c    = idx & 3;
        int lane = (idx >> 2) % G4;
        int n    = ((idx >> 2) / G4) % 20;
        int l    = (idx >> 2) / (G4 * 20);
        int j = n * 4 + c;
        int gate = j / 20, q = j % 20;
        int e = lane >> 2, q4 = lane & 3;
        int row = gate * H_ + e;
        int kk = 40 * q4 + 2 * q;
        float a, bvl;
        if (kk < H_) {
            if (l == 0) {
                a   = (kk     < IN_) ? Wih0[row * IN_ + kk]     : 0.f;
                bvl = (kk + 1 < IN_) ? Wih0[row * IN_ + kk + 1] : 0.f;
            } else {
                const float* p = WihR + ((size_t)(l - 1) * G4 + row) * H_;
                a = p[kk]; bvl = p[kk + 1];
            }
        } else {
            const float* p = Whh + ((size_t)l * G4 + row) * H_;
            a = p[kk - H_]; bvl = p[kk - H_ + 1];
        }
        h2 pa; pa[0] = (_Float16)a; pa[1] = (_Float16)bvl;
        w[idx] = __builtin_bit_cast(unsigned, pa);
    }
    if (idx < 2 * 10 * G4 * 4) {                       // 25600 dwords of tail weights
        int c = idx & 3, u4 = idx >> 2;
        int lane = u4 % G4, n = (u4 / G4) % 10, side = u4 / (G4 * 10);
        int j = n * 4 + c;
        int gate = j / 10, q = j % 10;
        int e = lane >> 2, q4 = lane & 3;
        int row = gate * H_ + e;
        int k0 = 20 * q4 + 2 * q;
        const float* p = (side == 0) ? WihR + ((size_t)8 * G4 + row) * H_
                                     : Whh  + ((size_t)9 * G4 + row) * H_;
        h2 pa; pa[0] = (_Float16)p[k0]; pa[1] = (_Float16)p[k0 + 1];
        tw[idx] = __builtin_bit_cast(unsigned, pa);
    }
    if (idx < L_ * G4) bbuf[idx] = bih[idx] + bhh[idx];
}

__global__ __launch_bounds__(TPB, 1) void lstm_stack_kernel(
    const float* __restrict__ x,      // [B,T,34]
    const uint4* __restrict__ w,      // wavefront weights
    const uint4* __restrict__ tw,     // tail (layer 9) weights
    const float* __restrict__ bbuf,   // [10][320]
    const float* __restrict__ fcw,    // [5,80]
    const float* __restrict__ fcb,    // [5]
    float* __restrict__ out)          // [B,5]
{
    const int b    = blockIdx.x;
    const int tid  = threadIdx.x;             // 0..959
    const int grp  = tid / G4;                // 0,1,2
    const int lane = tid - grp * G4;          // 0..319
    const int e    = lane >> 2;               // h element 0..79
    const int q4   = lane & 3;                // K-slice id == final gate id
    const int eS   = (e / 40) * 48 + (e % 40);
    const int eS24 = (e / 20) * 24 + (e % 20);

    const float mA  = (q4 == 2) ? -2.885390082f : -1.442695041f;
    const float bA  = (q4 == 2) ? 2.f : 1.f;
    const float cA0 = (q4 == 2) ? -1.f : 0.f;
    const bool  sel1 = (q4 & 1) != 0;
    const bool  sel2 = (q4 & 2) != 0;

    __shared__ __align__(16) _Float16 hist[T_][HPS];   // x then inter-pass h history
    __shared__ __align__(16) _Float16 ring[2][2][HPS]; // wavefront handoff
    __shared__ __align__(16) _Float16 hss[NG][2][HPS]; // per-group h ping-pong
    __shared__ __align__(16) float xp[4][4][84];       // tail xp ring
    __shared__ __align__(16) _Float16 hs9[2][4][24];   // tail h ping-pong (24-sliced)

    for (int j = tid; j < T_ * H_; j += TPB) {
        int t = j / H_, k = j % H_;
        float v = (k < IN_) ? x[((size_t)b * T_ + t) * IN_ + k] : 0.f;
        hist[t][(k / 40) * 48 + (k % 40)] = (_Float16)v;
    }

    // ================= passes 0..2: layers 0..8, wavefront-3 (R21/R22-proven) =================
    for (int pass = 0; pass < 3; ++pass) {
        const int l = NG * pass + grp;

        const uint4* wp = w + (size_t)l * 20 * G4 + lane;
        uint4 U0 = wp[0 * G4],  U1 = wp[1 * G4],  U2 = wp[2 * G4],  U3 = wp[3 * G4],  U4 = wp[4 * G4];
        uint4 U5 = wp[5 * G4],  U6 = wp[6 * G4],  U7 = wp[7 * G4],  U8 = wp[8 * G4],  U9 = wp[9 * G4];
        uint4 U10 = wp[10 * G4], U11 = wp[11 * G4], U12 = wp[12 * G4], U13 = wp[13 * G4], U14 = wp[14 * G4];
        uint4 U15 = wp[15 * G4], U16 = wp[16 * G4], U17 = wp[17 * G4], U18 = wp[18 * G4], U19 = wp[19 * G4];
        const float bias = bbuf[l * G4 + q4 * H_ + e];

        if (tid < 288) ((unsigned*)hss)[tid] = 0;
        __syncthreads();

        float cold = 0.f;

#pragma unroll 2
        for (int tick = 0; tick <= T_ + 1; ++tick) {
            const int tau = tick - grp;
            if (tau >= 0 && tau < T_) {
                const int par = tau & 1;
                const uint4* src;
                if (q4 < 2) src = (grp == 0) ? (const uint4*)(&hist[tau][48 * q4])
                                             : (const uint4*)(&ring[grp - 1][par][48 * q4]);
                else        src = (const uint4*)(&hss[grp][par][48 * (q4 - 2)]);
                uint4 M0 = src[0], M1 = src[1], M2 = src[2], M3 = src[3], M4 = src[4];
                h2 p0 = bc(M0.x), p1 = bc(M0.y), p2 = bc(M0.z), p3 = bc(M0.w);
                h2 p4 = bc(M1.x), p5 = bc(M1.y), p6 = bc(M1.z), p7 = bc(M1.w);
                h2 p8 = bc(M2.x), p9 = bc(M2.y), p10 = bc(M2.z), p11 = bc(M2.w);
                h2 p12 = bc(M3.x), p13 = bc(M3.y), p14 = bc(M3.z), p15 = bc(M3.w);
                h2 p16 = bc(M4.x), p17 = bc(M4.y), p18 = bc(M4.z), p19 = bc(M4.w);

                float aI = 0.f, aF = 0.f, aG = 0.f, aO = 0.f;
#define D(acc, W, C, P) acc = __builtin_amdgcn_fdot2(bc(W.C), P, acc, false);
                D(aI, U0, x, p0)  D(aI, U0, y, p1)  D(aI, U0, z, p2)  D(aI, U0, w, p3)
                D(aI, U1, x, p4)  D(aI, U1, y, p5)  D(aI, U1, z, p6)  D(aI, U1, w, p7)
                D(aI, U2, x, p8)  D(aI, U2, y, p9)  D(aI, U2, z, p10) D(aI, U2, w, p11)
                D(aI, U3, x, p12) D(aI, U3, y, p13) D(aI, U3, z, p14) D(aI, U3, w, p15)
                D(aI, U4, x, p16) D(aI, U4, y, p17) D(aI, U4, z, p18) D(aI, U4, w, p19)
                D(aF, U5, x, p0)  D(aF, U5, y, p1)  D(aF, U5, z, p2)  D(aF, U5, w, p3)
                D(aF, U6, x, p4)  D(aF, U6, y, p5)  D(aF, U6, z, p6)  D(aF, U6, w, p7)
                D(aF, U7, x, p8)  D(aF, U7, y, p9)  D(aF, U7, z, p10) D(aF, U7, w, p11)
                D(aF, U8, x, p12) D(aF, U8, y, p13) D(aF, U8, z, p14) D(aF, U8, w, p15)
                D(aF, U9, x, p16) D(aF, U9, y, p17) D(aF, U9, z, p18) D(aF, U9, w, p19)
                D(aG, U10, x, p0)  D(aG, U10, y, p1)  D(aG, U10, z, p2)  D(aG, U10, w, p3)
                D(aG, U11, x, p4)  D(aG, U11, y, p5)  D(aG, U11, z, p6)  D(aG, U11, w, p7)
                D(aG, U12, x, p8)  D(aG, U12, y, p9)  D(aG, U12, z, p10) D(aG, U12, w, p11)
                D(aG, U13, x, p12) D(aG, U13, y, p13) D(aG, U13, z, p14) D(aG, U13, w, p15)
                D(aG, U14, x, p16) D(aG, U14, y, p17) D(aG, U14, z, p18) D(aG, U14, w, p19)
                D(aO, U15, x, p0)  D(aO, U15, y, p1)  D(aO, U15, z, p2)  D(aO, U15, w, p3)
                D(aO, U16, x, p4)  D(aO, U16, y, p5)  D(aO, U16, z, p6)  D(aO, U16, w, p7)
                D(aO, U17, x, p8)  D(aO, U17, y, p9)  D(aO, U17, z, p10) D(aO, U17, w, p11)
                D(aO, U18, x, p12) D(aO, U18, y, p13) D(aO, U18, z, p14) D(aO, U18, w, p15)
                D(aO, U19, x, p16) D(aO, U19, y, p17) D(aO, U19, z, p18) D(aO, U19, w, p19)
#undef D
                float kI = sel1 ? aF : aI, oI = sel1 ? aI : aF;
                float AIF = kI + dpp_mov<0xB1>(oI);
                float kG = sel1 ? aO : aG, oG = sel1 ? aG : aO;
                float BGO = kG + dpp_mov<0xB1>(oG);
                float k2v = sel2 ? BGO : AIF, o2 = sel2 ? AIF : BGO;
                float S = k2v + dpp_mov<0x4E>(o2) + bias;

                float y   = __builtin_amdgcn_rcpf(1.f + __builtin_amdgcn_exp2f(mA * S));
                float act = __builtin_fmaf(bA, y, cA0);
                float t2v  = dpp_mov<0x4E>(act);
                float prod = act * t2v;
                float t3v  = dpp_mov<0xB1>(prod);
                float cnew = __builtin_fmaf(act, cold, t3v);
                float th   = __builtin_fmaf(2.f,
                               __builtin_amdgcn_rcpf(1.f + __builtin_amdgcn_exp2f(-2.885390082f * cnew)),
                               -1.f);
                float h = t2v * th;
                cold = cnew;

                if (q4 == 1) {
                    _Float16 h16 = (_Float16)h;
                    hss[grp][par ^ 1][eS] = h16;
                    if (grp == 2) hist[tau][eS] = h16;      // h^2 / h^5 / h^8 history
                    else          ring[grp][par][eS] = h16;
                }
            }
            __syncthreads();
        }
    }

    // ================= tail: layer 9 — chain (grp0, prio) + dual producers (grp1 even, grp2 odd) =================
    {
        const uint4* twp = tw + (size_t)((grp == 0) ? 1 : 0) * 10 * G4 + lane;
        uint4 V0 = twp[0 * G4], V1 = twp[1 * G4], V2 = twp[2 * G4], V3 = twp[3 * G4], V4 = twp[4 * G4];
        uint4 V5 = twp[5 * G4], V6 = twp[6 * G4], V7 = twp[7 * G4], V8 = twp[8 * G4], V9 = twp[9 * G4];
        const float bias9 = bbuf[9 * G4 + q4 * H_ + e];   // producers add it into xp

        if (tid < 96) ((unsigned*)hs9)[tid] = 0;          // h(-1)=0
        if (grp == 0) __builtin_amdgcn_s_setprio(1);      // chain gates every step

        float cold9 = 0.f;
        _Float16 h9 = (_Float16)0.f;

#define TDOTS(SPTR)                                                                  \
    const uint2* sp_ = (const uint2*)(SPTR);                                         \
    uint2 TA_ = sp_[0], TB_ = sp_[1], TC_ = sp_[2], TD_ = sp_[3], TE_ = sp_[4];      \
    h2 p0 = bc(TA_.x), p1 = bc(TA_.y), p2 = bc(TB_.x), p3 = bc(TB_.y);               \
    h2 p4 = bc(TC_.x), p5 = bc(TC_.y), p6 = bc(TD_.x), p7 = bc(TD_.y);               \
    h2 p8 = bc(TE_.x), p9 = bc(TE_.y);                                               \
    float aI = 0.f, aF = 0.f, aG = 0.f, aO = 0.f;                                    \
    aI = __builtin_amdgcn_fdot2(bc(V0.x), p0, aI, false);                            \
    aI = __builtin_amdgcn_fdot2(bc(V0.y), p1, aI, false);                            \
    aI = __builtin_amdgcn_fdot2(bc(V0.z), p2, aI, false);                            \
    aI = __builtin_amdgcn_fdot2(bc(V0.w), p3, aI, false);                            \
    aI = __builtin_amdgcn_fdot2(bc(V1.x), p4, aI, false);                            \
    aI = __builtin_amdgcn_fdot2(bc(V1.y), p5, aI, false);                            \
    aI = __builtin_amdgcn_fdot2(bc(V1.z), p6, aI, false);                            \
    aI = __builtin_amdgcn_fdot2(bc(V1.w), p7, aI, false);                            \
    aI = __builtin_amdgcn_fdot2(bc(V2.x), p8, aI, false);                            \
    aI = __builtin_amdgcn_fdot2(bc(V2.y), p9, aI, false);                            \
    aF = __builtin_amdgcn_fdot2(bc(V2.z), p0, aF, false);                            \
    aF = __builtin_amdgcn_fdot2(bc(V2.w), p1, aF, false);                            \
    aF = __builtin_amdgcn_fdot2(bc(V3.x), p2, aF, false);                            \
    aF = __builtin_amdgcn_fdot2(bc(V3.y), p3, aF, false);                            \
    aF = __builtin_amdgcn_fdot2(bc(V3.z), p4, aF, false);                            \
    aF = __builtin_amdgcn_fdot2(bc(V3.w), p5, aF, false);                            \
    aF = __builtin_amdgcn_fdot2(bc(V4.x), p6, aF, false);                            \
    aF = __builtin_amdgcn_fdot2(bc(V4.y), p7, aF, false);                            \
    aF = __builtin_amdgcn_fdot2(bc(V4.z), p8, aF, false);                            \
    aF = __builtin_amdgcn_fdot2(bc(V4.w), p9, aF, false);                            \
    aG = __builtin_amdgcn_fdot2(bc(V5.x), p0, aG, false);                            \
    aG = __builtin_amdgcn_fdot2(bc(V5.y), p1, aG, false);                            \
    aG = __builtin_amdgcn_fdot2(bc(V5.z), p2, aG, false);                            \
    aG = __builtin_amdgcn_fdot2(bc(V5.w), p3, aG, false);                            \
    aG = __builtin_amdgcn_fdot2(bc(V6.x), p4, aG, false);                            \
    aG = __builtin_amdgcn_fdot2(bc(V6.y), p5, aG, false);                            \
    aG = __builtin_amdgcn_fdot2(bc(V6.z), p6, aG, false);                            \
    aG = __builtin_amdgcn_fdot2(bc(V6.w), p7, aG, false);                            \
    aG = __builtin_amdgcn_fdot2(bc(V7.x), p8, aG, false);                            \
    aG = __builtin_amdgcn_fdot2(bc(V7.y), p9, aG, false);                            \
    aO = __builtin_amdgcn_fdot2(bc(V7.z), p0, aO, false);                            \
    aO = __builtin_amdgcn_fdot2(bc(V7.w), p1, aO, false);                            \
    aO = __builtin_amdgcn_fdot2(bc(V8.x), p2, aO, false);                            \
    aO = __builtin_amdgcn_fdot2(bc(V8.y), p3, aO, false);                            \
    aO = __builtin_amdgcn_fdot2(bc(V8.z), p4, aO, false);                            \
    aO = __builtin_amdgcn_fdot2(bc(V8.w), p5, aO, false);                            \
    aO = __builtin_amdgcn_fdot2(bc(V9.x), p6, aO, false);                            \
    aO = __builtin_amdgcn_fdot2(bc(V9.y), p7, aO, false);                            \
    aO = __builtin_amdgcn_fdot2(bc(V9.z), p8, aO, false);                            \
    aO = __builtin_amdgcn_fdot2(bc(V9.w), p9, aO, false);                            \
    float kI = sel1 ? aF : aI, oI = sel1 ? aI : aF;                                  \
    float AIF = kI + dpp_mov<0xB1>(oI);                                              \
    float kG = sel1 ? aO : aG, oG = sel1 ? aG : aO;                                  \
    float BGO = kG + dpp_mov<0xB1>(oG);                                              \
    float k2v = sel2 ? BGO : AIF, o2 = sel2 ? AIF : BGO;                             \
    float S = k2v + dpp_mov<0x4E>(o2);

#define TPRODUCE(TP) {                                                               \
    TDOTS(&hist[TP][q4 * 20 + (q4 >= 2 ? 8 : 0)])                                    \
    xp[(TP) & 3][q4][e] = S + bias9;                                                 \
}

        // prologue: P0 produces xp[0], P1 produces xp[1]
        if (grp == 1)      { TPRODUCE(0) }
        else if (grp == 2) { TPRODUCE(1) }
        __syncthreads();

#pragma unroll 2
        for (int t = 0; t < T_; ++t) {
            if (grp == 1) {
                int tp = t + 2;
                if (tp < T_ && !(tp & 1)) { TPRODUCE(tp) }   // even timesteps
            } else if (grp == 2) {
                int tp = t + 2;
                if (tp < T_ && (tp & 1)) { TPRODUCE(tp) }    // odd timesteps
            } else {
                const int par = t & 1;
                TDOTS(&hs9[par][q4][0])
                S += xp[t & 3][q4][e];

                float y   = __builtin_amdgcn_rcpf(1.f + __builtin_amdgcn_exp2f(mA * S));
                float act = __builtin_fmaf(bA, y, cA0);
                float t2v  = dpp_mov<0x4E>(act);
                float prod = act * t2v;
                float t3v  = dpp_mov<0xB1>(prod);
                float cnew = __builtin_fmaf(act, cold9, t3v);
                float th   = __builtin_fmaf(2.f,
                               __builtin_amdgcn_rcpf(1.f + __builtin_amdgcn_exp2f(-2.885390082f * cnew)),
                               -1.f);
                float h = t2v * th;
                cold9 = cnew;
                h9 = (_Float16)h;
                if (q4 == 1) hs9[par ^ 1][0][eS24] = h9;
            }
            __syncthreads();
        }
#undef TPRODUCE
#undef TDOTS

        if (grp == 0) __builtin_amdgcn_s_setprio(0);
        if (grp == 0 && q4 == 1) hist[T_ - 1][eS] = h9;    // h^9(T-1) for fc
        __syncthreads();
    }

    // ---- fc on final hidden state ----
    if (tid < NC_) {
        float acc = fcb[tid];
#pragma unroll
        for (int j = 0; j < H_; ++j)
            acc += fcw[tid * H_ + j] * (float)hist[T_ - 1][(j / 40) * 48 + (j % 40)];
        out[b * NC_ + tid] = acc;
    }
}

extern "C" void kernel_launch(void* const* d_in, const int* in_sizes, int n_in,
                              void* d_out, int out_size, void* d_ws, size_t ws_size,
                              hipStream_t stream) {
    const float* x    = (const float*)d_in[0];
    const float* Wih0 = (const float*)d_in[1];
    const float* WihR = (const float*)d_in[2];
    const float* Whh  = (const float*)d_in[3];
    const float* bih  = (const float*)d_in[4];
    const float* bhh  = (const float*)d_in[5];
    const float* fcw  = (const float*)d_in[6];
    const float* fcb  = (const float*)d_in[7];

    unsigned* w  = (unsigned*)d_ws;           // 256000 dwords
    float* bbuf  = (float*)(w + 256000);      // 3200 dwords
    unsigned* tw = (unsigned*)(bbuf + 3200);  // 25600 dwords

    prep_kernel<<<dim3(1000), dim3(256), 0, stream>>>(
        Wih0, WihR, Whh, bih, bhh, w, bbuf, tw);

    lstm_stack_kernel<<<dim3(B_), dim3(TPB), 0, stream>>>(
        x, (const uint4*)w, (const uint4*)tw, bbuf, fcw, fcb, (float*)d_out);
}

// Round 24
// 1659.451 us; speedup vs baseline: 1.0740x; 1.0740x over previous
//
#include <hip/hip_runtime.h>

#define B_   256
#define T_   512
#define IN_  34
#define H_   80
#define L_   10
#define NC_  5
#define G4   320
#define NG   3          // wavefront depth: 3 layer-groups (passes 0..2 = layers 0..8)
#define TPB  (NG * G4)  // 960
#define HPS  96         // row: 2 slices x 48 f16 (40 used + 8 pad)

typedef _Float16 h2 __attribute__((ext_vector_type(2)));

template <int CTRL>
__device__ __forceinline__ float dpp_mov(float v) {
    return __int_as_float(__builtin_amdgcn_update_dpp(0, __float_as_int(v), CTRL, 0xF, 0xF, true));
}
__device__ __forceinline__ h2 bc(unsigned u) { return __builtin_bit_cast(h2, u); }

// Wavefront weights: uint4 index (l*20 + n)*G4 + lane. lane = e*4+q4; slot j/20
// holds gate (slot ^ q4) — permuted so the reduce is a pure DPP butterfly.
// k = 40*q4 + 2*(j%20). Tail weights: slot j/10 holds gate (slot ^ q4), k0 = 20*q4+2*(j%10);
// side 0 = W_ih[9] (producers), side 1 = W_hh[9] (chain).
__global__ void prep_kernel(const float* __restrict__ Wih0, const float* __restrict__ WihR,
                            const float* __restrict__ Whh,  const float* __restrict__ bih,
                            const float* __restrict__ bhh,
                            unsigned* __restrict__ w, float* __restrict__ bbuf,
                            unsigned* __restrict__ tw) {
    int idx = blockIdx.x * 256 + threadIdx.x;          // dword index
    const int ND = L_ * 20 * G4 * 4;                   // 256000 dwords
    if (idx < ND) {
        int c    = idx & 3;
        int lane = (idx >> 2) % G4;
        int n    = ((idx >> 2) / G4) % 20;
        int l    = (idx >> 2) / (G4 * 20);
        int j = n * 4 + c;
        int slot = j / 20, q = j % 20;
        int e = lane >> 2, q4 = lane & 3;
        int row = (slot ^ q4) * H_ + e;                // permuted gate
        int kk = 40 * q4 + 2 * q;
        float a, bvl;
        if (kk < H_) {
            if (l == 0) {
                a   = (kk     < IN_) ? Wih0[row * IN_ + kk]     : 0.f;
                bvl = (kk + 1 < IN_) ? Wih0[row * IN_ + kk + 1] : 0.f;
            } else {
                const float* p = WihR + ((size_t)(l - 1) * G4 + row) * H_;
                a = p[kk]; bvl = p[kk + 1];
            }
        } else {
            const float* p = Whh + ((size_t)l * G4 + row) * H_;
            a = p[kk - H_]; bvl = p[kk - H_ + 1];
        }
        h2 pa; pa[0] = (_Float16)a; pa[1] = (_Float16)bvl;
        w[idx] = __builtin_bit_cast(unsigned, pa);
    }
    if (idx < 2 * 10 * G4 * 4) {                       // 25600 dwords of tail weights
        int c = idx & 3, u4 = idx >> 2;
        int lane = u4 % G4, n = (u4 / G4) % 10, side = u4 / (G4 * 10);
        int j = n * 4 + c;
        int slot = j / 10, q = j % 10;
        int e = lane >> 2, q4 = lane & 3;
        int row = (slot ^ q4) * H_ + e;                // permuted gate
        int k0 = 20 * q4 + 2 * q;
        const float* p = (side == 0) ? WihR + ((size_t)8 * G4 + row) * H_
                                     : Whh  + ((size_t)9 * G4 + row) * H_;
        h2 pa; pa[0] = (_Float16)p[k0]; pa[1] = (_Float16)p[k0 + 1];
        tw[idx] = __builtin_bit_cast(unsigned, pa);
    }
    if (idx < L_ * G4) bbuf[idx] = bih[idx] + bhh[idx];
}

__global__ __launch_bounds__(TPB, 1) void lstm_stack_kernel(
    const float* __restrict__ x,      // [B,T,34]
    const uint4* __restrict__ w,      // wavefront weights
    const uint4* __restrict__ tw,     // tail (layer 9) weights
    const float* __restrict__ bbuf,   // [10][320]
    const float* __restrict__ fcw,    // [5,80]
    const float* __restrict__ fcb,    // [5]
    float* __restrict__ out)          // [B,5]
{
    const int b    = blockIdx.x;
    const int tid  = threadIdx.x;             // 0..959
    const int grp  = tid / G4;                // 0,1,2
    const int lane = tid - grp * G4;          // 0..319
    const int e    = lane >> 2;               // h element 0..79
    const int q4   = lane & 3;                // K-slice id == final gate id
    const int eS   = (e / 40) * 48 + (e % 40);
    const int eS24 = (e / 20) * 24 + (e % 20);

    const float mA  = (q4 == 2) ? -2.885390082f : -1.442695041f;
    const float bA  = (q4 == 2) ? 2.f : 1.f;
    const float cA0 = (q4 == 2) ? -1.f : 0.f;

    __shared__ __align__(16) _Float16 hist[T_][HPS];   // x then inter-pass h history
    __shared__ __align__(16) _Float16 ring[2][2][HPS]; // wavefront handoff
    __shared__ __align__(16) _Float16 hss[NG][2][HPS]; // per-group h ping-pong
    __shared__ __align__(16) float xp[4][4][84];       // tail xp ring
    __shared__ __align__(16) _Float16 hs9[2][4][24];   // tail h ping-pong (24-sliced)

    for (int j = tid; j < T_ * H_; j += TPB) {
        int t = j / H_, k = j % H_;
        float v = (k < IN_) ? x[((size_t)b * T_ + t) * IN_ + k] : 0.f;
        hist[t][(k / 40) * 48 + (k % 40)] = (_Float16)v;
    }

    // ================= passes 0..2: layers 0..8, wavefront-3 =================
    for (int pass = 0; pass < 3; ++pass) {
        const int l = NG * pass + grp;

        const uint4* wp = w + (size_t)l * 20 * G4 + lane;
        uint4 U0 = wp[0 * G4],  U1 = wp[1 * G4],  U2 = wp[2 * G4],  U3 = wp[3 * G4],  U4 = wp[4 * G4];
        uint4 U5 = wp[5 * G4],  U6 = wp[6 * G4],  U7 = wp[7 * G4],  U8 = wp[8 * G4],  U9 = wp[9 * G4];
        uint4 U10 = wp[10 * G4], U11 = wp[11 * G4], U12 = wp[12 * G4], U13 = wp[13 * G4], U14 = wp[14 * G4];
        uint4 U15 = wp[15 * G4], U16 = wp[16 * G4], U17 = wp[17 * G4], U18 = wp[18 * G4], U19 = wp[19 * G4];
        const float bias = bbuf[l * G4 + q4 * H_ + e];   // gate q4 bias (lane ends with gate q4)

        if (tid < 288) ((unsigned*)hss)[tid] = 0;
        __syncthreads();

        float cold = 0.f;

#pragma unroll 2
        for (int tick = 0; tick <= T_ + 1; ++tick) {
            const int tau = tick - grp;
            if (tau >= 0 && tau < T_) {
                const int par = tau & 1;
                const uint4* src;
                if (q4 < 2) src = (grp == 0) ? (const uint4*)(&hist[tau][48 * q4])
                                             : (const uint4*)(&ring[grp - 1][par][48 * q4]);
                else        src = (const uint4*)(&hss[grp][par][48 * (q4 - 2)]);
                uint4 M0 = src[0], M1 = src[1], M2 = src[2], M3 = src[3], M4 = src[4];
                h2 p0 = bc(M0.x), p1 = bc(M0.y), p2 = bc(M0.z), p3 = bc(M0.w);
                h2 p4 = bc(M1.x), p5 = bc(M1.y), p6 = bc(M1.z), p7 = bc(M1.w);
                h2 p8 = bc(M2.x), p9 = bc(M2.y), p10 = bc(M2.z), p11 = bc(M2.w);
                h2 p12 = bc(M3.x), p13 = bc(M3.y), p14 = bc(M3.z), p15 = bc(M3.w);
                h2 p16 = bc(M4.x), p17 = bc(M4.y), p18 = bc(M4.z), p19 = bc(M4.w);

                float a0 = bias, a1 = 0.f, a2 = 0.f, a3 = 0.f;   // slot j = gate j^q4
#define D(acc, W, C, P) acc = __builtin_amdgcn_fdot2(bc(W.C), P, acc, false);
                D(a0, U0, x, p0)  D(a0, U0, y, p1)  D(a0, U0, z, p2)  D(a0, U0, w, p3)
                D(a0, U1, x, p4)  D(a0, U1, y, p5)  D(a0, U1, z, p6)  D(a0, U1, w, p7)
                D(a0, U2, x, p8)  D(a0, U2, y, p9)  D(a0, U2, z, p10) D(a0, U2, w, p11)
                D(a0, U3, x, p12) D(a0, U3, y, p13) D(a0, U3, z, p14) D(a0, U3, w, p15)
                D(a0, U4, x, p16) D(a0, U4, y, p17) D(a0, U4, z, p18) D(a0, U4, w, p19)
                D(a1, U5, x, p0)  D(a1, U5, y, p1)  D(a1, U5, z, p2)  D(a1, U5, w, p3)
                D(a1, U6, x, p4)  D(a1, U6, y, p5)  D(a1, U6, z, p6)  D(a1, U6, w, p7)
                D(a1, U7, x, p8)  D(a1, U7, y, p9)  D(a1, U7, z, p10) D(a1, U7, w, p11)
                D(a1, U8, x, p12) D(a1, U8, y, p13) D(a1, U8, z, p14) D(a1, U8, w, p15)
                D(a1, U9, x, p16) D(a1, U9, y, p17) D(a1, U9, z, p18) D(a1, U9, w, p19)
                D(a2, U10, x, p0)  D(a2, U10, y, p1)  D(a2, U10, z, p2)  D(a2, U10, w, p3)
                D(a2, U11, x, p4)  D(a2, U11, y, p5)  D(a2, U11, z, p6)  D(a2, U11, w, p7)
                D(a2, U12, x, p8)  D(a2, U12, y, p9)  D(a2, U12, z, p10) D(a2, U12, w, p11)
                D(a2, U13, x, p12) D(a2, U13, y, p13) D(a2, U13, z, p14) D(a2, U13, w, p15)
                D(a2, U14, x, p16) D(a2, U14, y, p17) D(a2, U14, z, p18) D(a2, U14, w, p19)
                D(a3, U15, x, p0)  D(a3, U15, y, p1)  D(a3, U15, z, p2)  D(a3, U15, w, p3)
                D(a3, U16, x, p4)  D(a3, U16, y, p5)  D(a3, U16, z, p6)  D(a3, U16, w, p7)
                D(a3, U17, x, p8)  D(a3, U17, y, p9)  D(a3, U17, z, p10) D(a3, U17, w, p11)
                D(a3, U18, x, p12) D(a3, U18, y, p13) D(a3, U18, z, p14) D(a3, U18, w, p15)
                D(a3, U19, x, p16) D(a3, U19, y, p17) D(a3, U19, z, p18) D(a3, U19, w, p19)
#undef D
                // pure-butterfly reduce-scatter: lane q4 ends with gate q4's total
                float r1 = a0 + dpp_mov<0xB1>(a1);
                float r2 = a2 + dpp_mov<0xB1>(a3);
                float S  = r1 + dpp_mov<0x4E>(r2);

                float y   = __builtin_amdgcn_rcpf(1.f + __builtin_amdgcn_exp2f(mA * S));
                float act = __builtin_fmaf(bA, y, cA0);
                float t2v  = dpp_mov<0x4E>(act);
                float prod = act * t2v;
                float t3v  = dpp_mov<0xB1>(prod);
                float cnew = __builtin_fmaf(act, cold, t3v);
                float th   = __builtin_fmaf(2.f,
                               __builtin_amdgcn_rcpf(1.f + __builtin_amdgcn_exp2f(-2.885390082f * cnew)),
                               -1.f);
                float h = t2v * th;
                cold = cnew;

                if (q4 == 1) {
                    _Float16 h16 = (_Float16)h;
                    hss[grp][par ^ 1][eS] = h16;
                    if (grp == 2) hist[tau][eS] = h16;
                    else          ring[grp][par][eS] = h16;
                }
            }
            __syncthreads();
        }
    }

    // ================= tail: layer 9 — chain (grp0, prio) + dual producers =================
    {
        const uint4* twp = tw + (size_t)((grp == 0) ? 1 : 0) * 10 * G4 + lane;
        uint4 V0 = twp[0 * G4], V1 = twp[1 * G4], V2 = twp[2 * G4], V3 = twp[3 * G4], V4 = twp[4 * G4];
        uint4 V5 = twp[5 * G4], V6 = twp[6 * G4], V7 = twp[7 * G4], V8 = twp[8 * G4], V9 = twp[9 * G4];
        const float bias9 = bbuf[9 * G4 + q4 * H_ + e];

        if (tid < 96) ((unsigned*)hs9)[tid] = 0;
        if (grp == 0) __builtin_amdgcn_s_setprio(1);

        float cold9 = 0.f;
        _Float16 h9 = (_Float16)0.f;

#define TDOTS(SPTR, INIT0)                                                           \
    const uint2* sp_ = (const uint2*)(SPTR);                                         \
    uint2 TA_ = sp_[0], TB_ = sp_[1], TC_ = sp_[2], TD_ = sp_[3], TE_ = sp_[4];      \
    h2 p0 = bc(TA_.x), p1 = bc(TA_.y), p2 = bc(TB_.x), p3 = bc(TB_.y);               \
    h2 p4 = bc(TC_.x), p5 = bc(TC_.y), p6 = bc(TD_.x), p7 = bc(TD_.y);               \
    h2 p8 = bc(TE_.x), p9 = bc(TE_.y);                                               \
    float a0 = (INIT0), a1 = 0.f, a2 = 0.f, a3 = 0.f;                                \
    a0 = __builtin_amdgcn_fdot2(bc(V0.x), p0, a0, false);                            \
    a0 = __builtin_amdgcn_fdot2(bc(V0.y), p1, a0, false);                            \
    a0 = __builtin_amdgcn_fdot2(bc(V0.z), p2, a0, false);                            \
    a0 = __builtin_amdgcn_fdot2(bc(V0.w), p3, a0, false);                            \
    a0 = __builtin_amdgcn_fdot2(bc(V1.x), p4, a0, false);                            \
    a0 = __builtin_amdgcn_fdot2(bc(V1.y), p5, a0, false);                            \
    a0 = __builtin_amdgcn_fdot2(bc(V1.z), p6, a0, false);                            \
    a0 = __builtin_amdgcn_fdot2(bc(V1.w), p7, a0, false);                            \
    a0 = __builtin_amdgcn_fdot2(bc(V2.x), p8, a0, false);                            \
    a0 = __builtin_amdgcn_fdot2(bc(V2.y), p9, a0, false);                            \
    a1 = __builtin_amdgcn_fdot2(bc(V2.z), p0, a1, false);                            \
    a1 = __builtin_amdgcn_fdot2(bc(V2.w), p1, a1, false);                            \
    a1 = __builtin_amdgcn_fdot2(bc(V3.x), p2, a1, false);                            \
    a1 = __builtin_amdgcn_fdot2(bc(V3.y), p3, a1, false);                            \
    a1 = __builtin_amdgcn_fdot2(bc(V3.z), p4, a1, false);                            \
    a1 = __builtin_amdgcn_fdot2(bc(V3.w), p5, a1, false);                            \
    a1 = __builtin_amdgcn_fdot2(bc(V4.x), p6, a1, false);                            \
    a1 = __builtin_amdgcn_fdot2(bc(V4.y), p7, a1, false);                            \
    a1 = __builtin_amdgcn_fdot2(bc(V4.z), p8, a1, false);                            \
    a1 = __builtin_amdgcn_fdot2(bc(V4.w), p9, a1, false);                            \
    a2 = __builtin_amdgcn_fdot2(bc(V5.x), p0, a2, false);                            \
    a2 = __builtin_amdgcn_fdot2(bc(V5.y), p1, a2, false);                            \
    a2 = __builtin_amdgcn_fdot2(bc(V5.z), p2, a2, false);                            \
    a2 = __builtin_amdgcn_fdot2(bc(V5.w), p3, a2, false);                            \
    a2 = __builtin_amdgcn_fdot2(bc(V6.x), p4, a2, false);                            \
    a2 = __builtin_amdgcn_fdot2(bc(V6.y), p5, a2, false);                            \
    a2 = __builtin_amdgcn_fdot2(bc(V6.z), p6, a2, false);                            \
    a2 = __builtin_amdgcn_fdot2(bc(V6.w), p7, a2, false);                            \
    a2 = __builtin_amdgcn_fdot2(bc(V7.x), p8, a2, false);                            \
    a2 = __builtin_amdgcn_fdot2(bc(V7.y), p9, a2, false);                            \
    a3 = __builtin_amdgcn_fdot2(bc(V7.z), p0, a3, false);                            \
    a3 = __builtin_amdgcn_fdot2(bc(V7.w), p1, a3, false);                            \
    a3 = __builtin_amdgcn_fdot2(bc(V8.x), p2, a3, false);                            \
    a3 = __builtin_amdgcn_fdot2(bc(V8.y), p3, a3, false);                            \
    a3 = __builtin_amdgcn_fdot2(bc(V8.z), p4, a3, false);                            \
    a3 = __builtin_amdgcn_fdot2(bc(V8.w), p5, a3, false);                            \
    a3 = __builtin_amdgcn_fdot2(bc(V9.x), p6, a3, false);                            \
    a3 = __builtin_amdgcn_fdot2(bc(V9.y), p7, a3, false);                            \
    a3 = __builtin_amdgcn_fdot2(bc(V9.z), p8, a3, false);                            \
    a3 = __builtin_amdgcn_fdot2(bc(V9.w), p9, a3, false);                            \
    float r1 = a0 + dpp_mov<0xB1>(a1);                                               \
    float r2 = a2 + dpp_mov<0xB1>(a3);                                               \
    float S  = r1 + dpp_mov<0x4E>(r2);

#define TPRODUCE(TP) {                                                               \
    TDOTS(&hist[TP][q4 * 20 + (q4 >= 2 ? 8 : 0)], bias9)                             \
    xp[(TP) & 3][q4][e] = S;                                                         \
}

        if (grp == 1)      { TPRODUCE(0) }
        else if (grp == 2) { TPRODUCE(1) }
        __syncthreads();

#pragma unroll 2
        for (int t = 0; t < T_; ++t) {
            if (grp == 1) {
                int tp = t + 2;
                if (tp < T_ && !(tp & 1)) { TPRODUCE(tp) }
            } else if (grp == 2) {
                int tp = t + 2;
                if (tp < T_ && (tp & 1)) { TPRODUCE(tp) }
            } else {
                const int par = t & 1;
                TDOTS(&hs9[par][q4][0], 0.f)
                S += xp[t & 3][q4][e];

                float y   = __builtin_amdgcn_rcpf(1.f + __builtin_amdgcn_exp2f(mA * S));
                float act = __builtin_fmaf(bA, y, cA0);
                float t2v  = dpp_mov<0x4E>(act);
                float prod = act * t2v;
                float t3v  = dpp_mov<0xB1>(prod);
                float cnew = __builtin_fmaf(act, cold9, t3v);
                float th   = __builtin_fmaf(2.f,
                               __builtin_amdgcn_rcpf(1.f + __builtin_amdgcn_exp2f(-2.885390082f * cnew)),
                               -1.f);
                float h = t2v * th;
                cold9 = cnew;
                h9 = (_Float16)h;
                if (q4 == 1) hs9[par ^ 1][0][eS24] = h9;
            }
            __syncthreads();
        }
#undef TPRODUCE
#undef TDOTS

        if (grp == 0) __builtin_amdgcn_s_setprio(0);
        if (grp == 0 && q4 == 1) hist[T_ - 1][eS] = h9;
        __syncthreads();
    }

    // ---- fc on final hidden state ----
    if (tid < NC_) {
        float acc = fcb[tid];
#pragma unroll
        for (int j = 0; j < H_; ++j)
            acc += fcw[tid * H_ + j] * (float)hist[T_ - 1][(j / 40) * 48 + (j % 40)];
        out[b * NC_ + tid] = acc;
    }
}

extern "C" void kernel_launch(void* const* d_in, const int* in_sizes, int n_in,
                              void* d_out, int out_size, void* d_ws, size_t ws_size,
                              hipStream_t stream) {
    const float* x    = (const float*)d_in[0];
    const float* Wih0 = (const float*)d_in[1];
    const float* WihR = (const float*)d_in[2];
    const float* Whh  = (const float*)d_in[3];
    const float* bih  = (const float*)d_in[4];
    const float* bhh  = (const float*)d_in[5];
    const float* fcw  = (const float*)d_in[6];
    const float* fcb  = (const float*)d_in[7];

    unsigned* w  = (unsigned*)d_ws;           // 256000 dwords
    float* bbuf  = (float*)(w + 256000);      // 3200 dwords
    unsigned* tw = (unsigned*)(bbuf + 3200);  // 25600 dwords

    prep_kernel<<<dim3(1000), dim3(256), 0, stream>>>(
        Wih0, WihR, Whh, bih, bhh, w, bbuf, tw);

    lstm_stack_kernel<<<dim3(B_), dim3(TPB), 0, stream>>>(
        x, (const uint4*)w, (const uint4*)tw, bbuf, fcw, fcb, (float*)d_out);
}